// Round 6
// baseline (146.014 us; speedup 1.0000x reference)
//
#include <hip/hip_runtime.h>

typedef _Float16 f16;
typedef unsigned short u16;
typedef __attribute__((ext_vector_type(8))) f16 f16x8;
typedef __attribute__((ext_vector_type(4))) f16 f16x4;
typedef __attribute__((ext_vector_type(4))) float floatx4;

#define NPIX 4096
#define KT   128          // keys per attention tile
#define NT   (NPIX / KT)  // 32 key tiles
// V fragment-major layout, per bh: [kt(32)][c(8)][dh(2)][quad(4)][l16(16)][j(4)]
// element (key,d): kt=key>>7, c=(key>>4)&7, quad=(key>>2)&3, j=key&3,
//                  dh=d>>4, l16=d&15.  Per (kt,c,dh): 64 lanes x 8B = 512 B
// contiguous -> every attn V load is one fully-coalesced dwordx2.
#define VBH  131072       // f16 per bh (32*4096)

// ---------------------------------------------------------------------------
// Kernel 1: QKV projection as fp16 MFMA GEMM.
// All types now use the C[p][o] orientation (A = X^T frags, B = W frags).
// Q/K stores unchanged. V stores packed f16x4 over r (= 4 consecutive keys)
// into the fragment-major layout -> 4 perfectly-coalesced 512B stores
// (was 16 scalar f16 stores).
// grid (64 p-tiles, 6 o-tiles of 64, 4 b), block 256 (4 waves).
// ---------------------------------------------------------------------------
__global__ __launch_bounds__(256) void qkv_mfma(
    const float* __restrict__ x, const float* __restrict__ w,
    f16* __restrict__ qh, f16* __restrict__ kh, f16* __restrict__ vfrag)
{
    __shared__ f16 wlds[64 * 136];     // [o][c] padded (+8) -> conflict-free frags
    const int tid  = threadIdx.x;
    const int wave = tid >> 6;
    const int lane = tid & 63;
    const int quad = lane >> 4;
    const int l16  = lane & 15;
    const int pbase = blockIdx.x * 64;
    const int y     = blockIdx.y;      // o-tile of 64; type = y>>1
    const int b     = blockIdx.z;

#pragma unroll
    for (int i = 0; i < 8; ++i) {
        int idx = i * 256 + tid;               // 2048 float4
        int o = idx >> 5, ch = idx & 31;
        float4 wv = *(const float4*)(w + (size_t)(y * 64 + o) * 128 + ch * 4);
        f16x4 h; h[0] = (f16)wv.x; h[1] = (f16)wv.y; h[2] = (f16)wv.z; h[3] = (f16)wv.w;
        *(f16x4*)&wlds[o * 136 + ch * 4] = h;
    }
    __syncthreads();

    const float* xb = x + (size_t)b * 128 * NPIX;
    const int type = y >> 1;                   // 0=q 1=k 2=v

    // ---- C[p][o]: A = X^T (global), B = W (LDS) ----
    const int p_row = pbase + wave * 16 + l16;
    f16x8 af[4];
#pragma unroll
    for (int kc = 0; kc < 4; ++kc) {
        const int c0 = kc * 32 + quad * 8;
#pragma unroll
        for (int j = 0; j < 8; ++j)
            af[kc][j] = (f16)xb[(size_t)(c0 + j) * NPIX + p_row];
    }
    floatx4 acc[4];
#pragma unroll
    for (int n = 0; n < 4; ++n) acc[n] = floatx4{0.f, 0.f, 0.f, 0.f};
#pragma unroll
    for (int n = 0; n < 4; ++n)
#pragma unroll
        for (int kc = 0; kc < 4; ++kc) {
            f16x8 bf = *(const f16x8*)&wlds[(n * 16 + l16) * 136 + kc * 32 + quad * 8];
            acc[n] = __builtin_amdgcn_mfma_f32_16x16x32_f16(af[kc], bf, acc[n], 0, 0, 0);
        }

    if (type < 2) {
        const float qs = (type == 0) ? 0.17677669529663687f * 1.4426950408889634f : 1.0f;
        f16* dst = (type == 0) ? qh : kh;
#pragma unroll
        for (int n = 0; n < 4; ++n) {
            const int og   = y * 64 + n * 16 + l16;
            const int head = (og >> 5) & 3;
            const int d    = og & 31;
            f16* base = dst + (size_t)(b * 4 + head) * NPIX * 32;
#pragma unroll
            for (int r = 0; r < 4; ++r) {
                const int p = pbase + wave * 16 + quad * 4 + r;
                base[(size_t)p * 32 + d] = (f16)(acc[n][r] * qs);
            }
        }
    } else {
        // V: lane holds keys p = pq + quad*4 + r (r packs j), d = ogv per n.
        const int pq = pbase + wave * 16;          // wave-uniform
        const int kt = pq >> 7, c = (pq >> 4) & 7;
#pragma unroll
        for (int n = 0; n < 4; ++n) {
            const int head = (y - 4) * 2 + (n >> 1);
            const int bh_n = b * 4 + head;
            const size_t off = (size_t)bh_n * VBH + (size_t)kt * 4096 + c * 512
                             + (n & 1) * 256 + quad * 64 + l16 * 4;
            f16x4 hv;
#pragma unroll
            for (int r = 0; r < 4; ++r) hv[r] = (f16)acc[n][r];
            *(f16x4*)(vfrag + off) = hv;
        }
    }
}

// ---------------------------------------------------------------------------
// Kernel 2: flash attention — v6: NO LDS, NO BARRIERS, all operands direct
// from global in fragment-native layouts.
//   K A-frag: kh[bh][key][32]      -> 16B/lane, contiguous 1KB per instr
//   V B-frag: vfrag fragment-major ->  8B/lane, contiguous 512B per instr
// (v4 failed ONLY because V-from-global was a 16-segment scatter; the layout
// change fixes that. v5 proved direct K is benign: conflicts -2.1M, FETCH
// unchanged.) No barriers -> the CU's 8 waves desync naturally, so one
// wave's exp (VALU/trans) overlaps another's MFMA — the overlap lockstep
// provably prevented. K register ping-pong prefetch (v5); V loads issued at
// body start, consumed after QK+exp (~1000cy later) -> latency hidden.
// grid (32 q-blocks of 128, 16 bh), block 256 (4 waves x 32 q).
// ---------------------------------------------------------------------------
#define ATTN_STEP(KF, KFN, T, TNXT)                                            \
{                                                                              \
    /* V frags for current tile: 16 coalesced dwordx2 loads (used in PV) */    \
    f16x4 vf[8][2];                                                            \
    _Pragma("unroll")                                                          \
    for (int c = 0; c < 8; ++c) {                                              \
        _Pragma("unroll")                                                      \
        for (int dh = 0; dh < 2; ++dh)                                         \
            vf[c][dh] = *(const f16x4*)(vp + (size_t)(T) * 4096 + c * 512 + dh * 256); \
    }                                                                          \
    /* prefetch next K tile's fragments (consumed next step) */                \
    if ((TNXT) < NT) {                                                         \
        _Pragma("unroll")                                                      \
        for (int t = 0; t < 8; ++t)                                            \
            KFN[t] = *(const f16x8*)(kp + (size_t)((TNXT) * KT + t * 16) * 32);\
    }                                                                          \
    /* S^T for BOTH q-subtiles (16 MFMA back-to-back) */                       \
    floatx4 st0[8], st1[8];                                                    \
    _Pragma("unroll")                                                          \
    for (int t = 0; t < 8; ++t) {                                              \
        floatx4 z = {0.f, 0.f, 0.f, 0.f};                                      \
        st0[t] = __builtin_amdgcn_mfma_f32_16x16x32_f16(KF[t], qB[0], z, 0, 0, 0); \
    }                                                                          \
    _Pragma("unroll")                                                          \
    for (int t = 0; t < 8; ++t) {                                              \
        floatx4 z = {0.f, 0.f, 0.f, 0.f};                                      \
        st1[t] = __builtin_amdgcn_mfma_f32_16x16x32_f16(KF[t], qB[1], z, 0, 0, 0); \
    }                                                                          \
    /* exp(h0) on VALU (overlaps tail of QK(h1) on MFMA pipe) */               \
    f16x4 pf0[8], pf1[8];                                                      \
    float ls0 = 0.f, ls1 = 0.f;                                                \
    _Pragma("unroll")                                                          \
    for (int c = 0; c < 8; ++c) {                                              \
        float e0 = __builtin_amdgcn_exp2f(st0[c][0]);                          \
        float e1 = __builtin_amdgcn_exp2f(st0[c][1]);                          \
        float e2 = __builtin_amdgcn_exp2f(st0[c][2]);                          \
        float e3 = __builtin_amdgcn_exp2f(st0[c][3]);                          \
        ls0 += (e0 + e1) + (e2 + e3);                                          \
        pf0[c][0] = (f16)e0; pf0[c][1] = (f16)e1;                              \
        pf0[c][2] = (f16)e2; pf0[c][3] = (f16)e3;                              \
    }                                                                          \
    /* PV(h0) MFMAs interleaved with exp(h1) VALU: both pipes busy */          \
    _Pragma("unroll")                                                          \
    for (int c = 0; c < 8; ++c) {                                              \
        oacc[0][0] = __builtin_amdgcn_mfma_f32_16x16x16f16(pf0[c], vf[c][0], oacc[0][0], 0, 0, 0); \
        oacc[0][1] = __builtin_amdgcn_mfma_f32_16x16x16f16(pf0[c], vf[c][1], oacc[0][1], 0, 0, 0); \
        float e0 = __builtin_amdgcn_exp2f(st1[c][0]);                          \
        float e1 = __builtin_amdgcn_exp2f(st1[c][1]);                          \
        float e2 = __builtin_amdgcn_exp2f(st1[c][2]);                          \
        float e3 = __builtin_amdgcn_exp2f(st1[c][3]);                          \
        ls1 += (e0 + e1) + (e2 + e3);                                          \
        pf1[c][0] = (f16)e0; pf1[c][1] = (f16)e1;                              \
        pf1[c][2] = (f16)e2; pf1[c][3] = (f16)e3;                              \
    }                                                                          \
    lsum[0] += ls0; lsum[1] += ls1;                                            \
    _Pragma("unroll")                                                          \
    for (int c = 0; c < 8; ++c) {                                              \
        oacc[1][0] = __builtin_amdgcn_mfma_f32_16x16x16f16(pf1[c], vf[c][0], oacc[1][0], 0, 0, 0); \
        oacc[1][1] = __builtin_amdgcn_mfma_f32_16x16x16f16(pf1[c], vf[c][1], oacc[1][1], 0, 0, 0); \
    }                                                                          \
}

__global__ __launch_bounds__(256, 2) void attn_kernel(
    const f16* __restrict__ qh, const f16* __restrict__ kh,
    const f16* __restrict__ vfrag, f16* __restrict__ att)
{
    const int tid  = threadIdx.x;
    const int wave = tid >> 6;
    const int lane = tid & 63;
    const int quad = lane >> 4;
    const int l16  = lane & 15;
    const int bh   = blockIdx.y;
    const int qbase = blockIdx.x * 128 + wave * 32;

    // per-lane fragment pointers
    const f16* kp = kh + (size_t)bh * NPIX * 32 + (size_t)l16 * 32 + quad * 8;
    const f16* vp = vfrag + (size_t)bh * VBH + (size_t)lane * 4;

    // Q B-frags (B[k=d][n=q]): two 16-q subtiles
    f16x8 qB[2];
#pragma unroll
    for (int h = 0; h < 2; ++h)
        qB[h] = *(const f16x8*)(qh + ((size_t)bh * NPIX + qbase + h * 16 + l16) * 32 + quad * 8);

    floatx4 oacc[2][2];
#pragma unroll
    for (int h = 0; h < 2; ++h)
#pragma unroll
        for (int dh = 0; dh < 2; ++dh) oacc[h][dh] = floatx4{0.f, 0.f, 0.f, 0.f};
    float lsum[2] = {0.f, 0.f};

    // prologue: K tile 0 frags -> kfA
    f16x8 kfA[8], kfB[8];
#pragma unroll
    for (int t = 0; t < 8; ++t)
        kfA[t] = *(const f16x8*)(kp + (size_t)(t * 16) * 32);

    for (int it = 0; it < NT / 2; ++it) {
        const int t0 = it * 2;
        ATTN_STEP(kfA, kfB, t0,     t0 + 1);
        ATTN_STEP(kfB, kfA, t0 + 1, t0 + 2);
    }

    // epilogue: reduce lsum across quads (q lives in l16), divide, store f16
#pragma unroll
    for (int h = 0; h < 2; ++h) {
        float l = lsum[h];
        l += __shfl_xor(l, 16);
        l += __shfl_xor(l, 32);
        const float inv = 1.0f / l;            // valid per q = l16
#pragma unroll
        for (int r = 0; r < 4; ++r) {
            const float invr = __shfl(inv, quad * 4 + r);   // inv for q-row quad*4+r
            const int q = qbase + h * 16 + quad * 4 + r;
            f16* ob = att + ((size_t)bh * NPIX + q) * 32;
            ob[l16]      = (f16)(oacc[h][0][r] * invr);
            ob[16 + l16] = (f16)(oacc[h][1][r] * invr);
        }
    }
}

// ---------------------------------------------------------------------------
// Kernel 3: output projection as fp16 MFMA GEMM.  (round-0 form, known-good)
// C[o][p] = Wp[o][c] * att^T[c][p] + bias; att[bh][p][32] IS the natural
// B-fragment layout (16B contiguous per lane). Stores coalesced fp32.
// grid (64 p-tiles, 4 b), block 256 (4 waves).
// ---------------------------------------------------------------------------
__global__ __launch_bounds__(256) void proj_mfma(
    const f16* __restrict__ att, const float* __restrict__ wp,
    const float* __restrict__ bp, float* __restrict__ out)
{
    __shared__ f16 wplds[128 * 136];   // [o][c] padded, 34.8 KB
    __shared__ float bplds[128];
    const int tid  = threadIdx.x;
    const int wave = tid >> 6;
    const int lane = tid & 63;
    const int quad = lane >> 4;
    const int l16  = lane & 15;
    const int pbase = blockIdx.x * 64;
    const int b     = blockIdx.y;

    if (tid < 128) bplds[tid] = bp[tid];
#pragma unroll
    for (int i = 0; i < 16; ++i) {
        int idx = i * 256 + tid;               // 4096 float4 = 128*128 floats
        int o = idx >> 5, ch = idx & 31;
        float4 wv = *(const float4*)(wp + (size_t)o * 128 + ch * 4);
        f16x4 h; h[0] = (f16)wv.x; h[1] = (f16)wv.y; h[2] = (f16)wv.z; h[3] = (f16)wv.w;
        *(f16x4*)&wplds[o * 136 + ch * 4] = h;
    }
    __syncthreads();

    const f16* ab = att + (size_t)b * 4 * NPIX * 32;
    const int p_col = pbase + wave * 16 + l16;
    f16x8 bf[4];
#pragma unroll
    for (int kc = 0; kc < 4; ++kc)
        bf[kc] = *(const f16x8*)(ab + ((size_t)kc * NPIX + p_col) * 32 + quad * 8);

    floatx4 acc[8];
#pragma unroll
    for (int m = 0; m < 8; ++m) acc[m] = floatx4{0.f, 0.f, 0.f, 0.f};
#pragma unroll
    for (int m = 0; m < 8; ++m)
#pragma unroll
        for (int kc = 0; kc < 4; ++kc) {
            f16x8 af = *(const f16x8*)&wplds[(m * 16 + l16) * 136 + kc * 32 + quad * 8];
            acc[m] = __builtin_amdgcn_mfma_f32_16x16x32_f16(af, bf[kc], acc[m], 0, 0, 0);
        }

#pragma unroll
    for (int m = 0; m < 8; ++m)
#pragma unroll
        for (int r = 0; r < 4; ++r) {
            const int o = m * 16 + quad * 4 + r;
            out[((size_t)b * 128 + o) * NPIX + p_col] = acc[m][r] + bplds[o];
        }
}

// ---------------------------------------------------------------------------
extern "C" void kernel_launch(void* const* d_in, const int* in_sizes, int n_in,
                              void* d_out, int out_size, void* d_ws, size_t ws_size,
                              hipStream_t stream)
{
    const float* x      = (const float*)d_in[0];
    const float* w_qkv  = (const float*)d_in[1];
    const float* w_proj = (const float*)d_in[2];
    const float* b_proj = (const float*)d_in[3];
    float* out = (float*)d_out;

    char* ws = (char*)d_ws;
    f16* qh    = (f16*)(ws);                // 4 MB [bh][p][32], pre-scaled
    f16* kh    = (f16*)(ws + (4u << 20));   // 4 MB [bh][p][32]
    f16* vfrag = (f16*)(ws + (8u << 20));   // 4 MB fragment-major V
    f16* att   = (f16*)(ws + (12u << 20));  // 4 MB [bh][p][32]

    qkv_mfma<<<dim3(64, 6, 4), 256, 0, stream>>>(x, w_qkv, qh, kh, vfrag);
    attn_kernel<<<dim3(32, 16, 1), 256, 0, stream>>>(qh, kh, vfrag, att);
    proj_mfma<<<dim3(64, 4, 1), 256, 0, stream>>>(att, w_proj, b_proj, out);
}